// Round 9
// baseline (1036.801 us; speedup 1.0000x reference)
//
#include <hip/hip_runtime.h>
#include <math.h>

static constexpr int N_NODES = 100000;
static constexpr int N_EDGES = 1600000;
static constexpr int E_TOT   = N_NODES + N_EDGES;   // edges + self-loops
static constexpr int D   = 512;
static constexpr int FIN = 182;
static constexpr int K1P = 192;                     // FIN padded to mult of 32
static constexpr int M_PAD = 100096;                // 782 * 128
static constexpr int N_BANDS = M_PAD / 128;         // 782
static constexpr float NEG_SLOPE = 0.2f;
static constexpr float LN_EPS = 1e-5f;

typedef __attribute__((ext_vector_type(8))) short short8;
typedef __attribute__((ext_vector_type(4))) float floatx4;

// ---------------- bf16 helpers (storage type: unsigned short) ----------------
__device__ __forceinline__ unsigned short f2bf(float f) {
  unsigned int x = __builtin_bit_cast(unsigned int, f);
  x += 0x7fffu + ((x >> 16) & 1u);   // round-to-nearest-even
  return (unsigned short)(x >> 16);
}
__device__ __forceinline__ void unpack2(unsigned int w, float& lo, float& hi) {
  lo = __builtin_bit_cast(float, w << 16);
  hi = __builtin_bit_cast(float, w & 0xffff0000u);
}

// async global->LDS, 16B per lane; LDS dest = wave-uniform base + lane*16
typedef __attribute__((address_space(1))) const void gv_t;
typedef __attribute__((address_space(3))) void lv_t;
__device__ __forceinline__ void gll16(const void* g, void* l) {
  __builtin_amdgcn_global_load_lds((gv_t*)g, (lv_t*)l, 16, 0, 0);
}

// ---------------------------------------------------------------------------
// init + edge-index dtype probe (single block, sampled, no atomic storm)
// ---------------------------------------------------------------------------
__global__ __launch_bounds__(256) void k_init(int* __restrict__ deg,
                                              int* __restrict__ counter,
                                              int* __restrict__ flag) {
  int i = blockIdx.x * 256 + threadIdx.x;
  if (i < N_NODES) deg[i] = 0;
  if (i == 0) { *counter = 0; *flag = 0; }
}

__global__ __launch_bounds__(256) void k_detect(const int* __restrict__ ei,
                                                int* __restrict__ flag) {
  bool nz = false;
#pragma unroll
  for (int r = 0; r < 8; ++r) {
    int i = threadIdx.x + r * 256;          // sample edges 0..2047
    nz |= (ei[2 * i + 1] != 0);
  }
  __shared__ int sh[4];
  int wv = threadIdx.x >> 6;
  if ((threadIdx.x & 63) == 0) sh[wv] = 0;
  __syncthreads();
  if (__any(nz) && (threadIdx.x & 63) == 0) sh[wv] = 1;
  __syncthreads();
  if (threadIdx.x == 0) *flag = sh[0] | sh[1] | sh[2] | sh[3];
}

__device__ __forceinline__ int edge_src(const int* ei, int f, int i) {
  return f ? ei[i] : ei[2 * i];
}
__device__ __forceinline__ int edge_dst(const int* ei, int f, int i) {
  return f ? ei[N_EDGES + i] : ei[2 * (N_EDGES + i)];
}

// ---------------------------------------------------------------------------
// CSR build grouped by dst (range order irrelevant -> atomic range alloc)
// ---------------------------------------------------------------------------
__global__ __launch_bounds__(256) void k_count(const int* __restrict__ ei,
                                               const int* __restrict__ flag,
                                               int* __restrict__ deg) {
  int i = blockIdx.x * 256 + threadIdx.x;
  if (i >= E_TOT) return;
  int f = *flag;
  int d = (i < N_EDGES) ? edge_dst(ei, f, i) : (i - N_EDGES);
  atomicAdd(deg + d, 1);
}

__global__ __launch_bounds__(256) void k_alloc(const int* __restrict__ deg,
                                               int* __restrict__ off,
                                               int* __restrict__ pos,
                                               int* __restrict__ counter) {
  int i = blockIdx.x * 256 + threadIdx.x;
  if (i >= N_NODES) return;
  int r = atomicAdd(counter, deg[i]);
  off[i] = r;
  pos[i] = r;
}

__global__ __launch_bounds__(256) void k_fill(const int* __restrict__ ei,
                                              const int* __restrict__ flag,
                                              int* __restrict__ pos,
                                              int* __restrict__ csr_src) {
  int i = blockIdx.x * 256 + threadIdx.x;
  if (i >= E_TOT) return;
  int f = *flag;
  int s, d;
  if (i < N_EDGES) { s = edge_src(ei, f, i); d = edge_dst(ei, f, i); }
  else             { s = d = i - N_EDGES; }
  int slot = atomicAdd(pos + d, 1);
  csr_src[slot] = s;
}

// ---------------------------------------------------------------------------
// conversion / init kernels (one-shot, tiny)
// ---------------------------------------------------------------------------
__global__ __launch_bounds__(256) void k_cvt_x(const float* __restrict__ x,
                                               unsigned short* __restrict__ xb) {
  int i = blockIdx.x * 256 + threadIdx.x;
  if (i >= N_NODES * K1P) return;
  int row = i / K1P, col = i - row * K1P;
  float v = (col < FIN) ? x[(size_t)row * FIN + col] : 0.f;
  xb[i] = f2bf(v);
}

__global__ __launch_bounds__(256) void k_cvt_wt(const float* __restrict__ W,
                                                unsigned short* __restrict__ Wt,
                                                int K, int Kpad) {
  int i = blockIdx.x * 256 + threadIdx.x;
  if (i >= 512 * Kpad) return;
  int n = i / Kpad, k = i - n * Kpad;
  Wt[i] = f2bf(k < K ? W[(size_t)k * 512 + n] : 0.f);
}

__global__ __launch_bounds__(256) void k_out_init(const float* __restrict__ bc2,
                                                  float* __restrict__ out) {
  int i = blockIdx.x * 256 + threadIdx.x;
  if (i < N_NODES) {
    float2 v; v.x = bc2[0]; v.y = bc2[1];
    ((float2*)out)[i] = v;
  }
}

__global__ __launch_bounds__(256) void k_zero(float* __restrict__ a,
                                              float* __restrict__ b) {
  int i = blockIdx.x * 256 + threadIdx.x;
  if (i < N_NODES * 4) { a[i] = 0.f; b[i] = 0.f; }
}

// ---------------------------------------------------------------------------
// XCD-swizzled band decode: the 4 col-blocks of one 128-row band get block
// ids congruent mod 8 -> same XCD (id%8 round-robin heuristic) -> the A band
// is fetched once into that XCD's L2 instead of 4x. 8*ceil(782/8)*4 = 3136
// blocks; bands >= 782 exit early (uniform, before any barrier).
// ---------------------------------------------------------------------------
__device__ __forceinline__ bool band_decode(int& bm, int& bn) {
  const int id  = blockIdx.x;
  const int kk  = id >> 3;
  const int band = (kk >> 2) * 8 + (id & 7);
  if (band >= N_BANDS) return false;
  bm = band * 128;
  bn = (kk & 3) * 128;
  return true;
}

// ---------------------------------------------------------------------------
// Fused GEMM + attention-dots + int8 row-quantization.
// mfma operands SWAPPED (HW-verified round 6): lane holds
//   m = bm+wm+im*16+r (4 rows), n = bn+wn+in*16+q*4+rr (4 consecutive cols).
// Epilogue per lane: per-row absmax (q-butterfly + LDS cross-wave combine),
// int8 quantize -> packed 4B stores into h8; s_src/s_dst partial dots
// (q-butterfly, one atomicAdd per row per wave). No bf16 C materialization.
// bn spans exactly one head (bn>>7). s_src/s_dst must be pre-zeroed.
// ---------------------------------------------------------------------------
__global__ __launch_bounds__(256)
void gemm_fused(const unsigned short* __restrict__ A,
                const unsigned short* __restrict__ Bt,
                const float* __restrict__ a_src,
                const float* __restrict__ a_dst,
                unsigned char* __restrict__ h8,
                float* __restrict__ scales4,
                float* __restrict__ s_src,
                float* __restrict__ s_dst,
                int lda)
{
  __shared__ unsigned short As[128 * 32];   // [m][k] 8 KB
  __shared__ unsigned short Bs[128 * 32];   // [n][k] 8 KB
  __shared__ float sMax[2][128];
  int bm, bn;
  if (!band_decode(bm, bn)) return;
  const int t    = threadIdx.x;
  const int w    = t >> 6;
  const int lane = t & 63;
  const int r    = lane & 15;
  const int q    = lane >> 4;
  const int wm   = (w >> 1) * 64;
  const int wn   = (w & 1) * 64;
  const int half = wn >> 6;
  const int head = bn >> 7;

  const int ch0 = (w * 2 + 0) * 64 + lane;
  const int ch1 = (w * 2 + 1) * 64 + lane;
  const unsigned short* gA0 = A + (size_t)(bm + (ch0 >> 2)) * lda + (ch0 & 3) * 8;
  const unsigned short* gA1 = A + (size_t)(bm + (ch1 >> 2)) * lda + (ch1 & 3) * 8;
  const unsigned short* gB0 = Bt + (size_t)(bn + (ch0 >> 2)) * lda + (ch0 & 3) * 8;
  const unsigned short* gB1 = Bt + (size_t)(bn + (ch1 >> 2)) * lda + (ch1 & 3) * 8;
  unsigned short* lA0 = As + (w * 2 + 0) * 512;
  unsigned short* lA1 = As + (w * 2 + 1) * 512;
  unsigned short* lB0 = Bs + (w * 2 + 0) * 512;
  unsigned short* lB1 = Bs + (w * 2 + 1) * 512;

  floatx4 acc[4][4] = {};

  for (int k0 = 0; k0 < lda; k0 += 32) {
    gll16(gA0 + k0, lA0);
    gll16(gA1 + k0, lA1);
    gll16(gB0 + k0, lB0);
    gll16(gB1 + k0, lB1);
    __syncthreads();

    short8 af[4], bfr[4];
#pragma unroll
    for (int im = 0; im < 4; ++im)
      af[im] = *(const short8*)(As + (wm + im * 16 + r) * 32 + q * 8);
#pragma unroll
    for (int in = 0; in < 4; ++in)
      bfr[in] = *(const short8*)(Bs + (wn + in * 16 + r) * 32 + q * 8);
#pragma unroll
    for (int im = 0; im < 4; ++im)
#pragma unroll
      for (int in = 0; in < 4; ++in)
        acc[im][in] = __builtin_amdgcn_mfma_f32_16x16x32_bf16(
            bfr[in], af[im], acc[im][in], 0, 0, 0);   // swapped operands
    __syncthreads();
  }

  // ---- per-row absmax over this wave's 64 cols, then cross-wave via LDS ----
  float am[4];
#pragma unroll
  for (int im = 0; im < 4; ++im) {
    float a = 0.f;
#pragma unroll
    for (int in = 0; in < 4; ++in)
#pragma unroll
      for (int rr = 0; rr < 4; ++rr)
        a = fmaxf(a, fabsf(acc[im][in][rr]));
    a = fmaxf(a, __shfl_xor(a, 16));
    a = fmaxf(a, __shfl_xor(a, 32));
    am[im] = a;
  }
  if (q == 0) {
#pragma unroll
    for (int im = 0; im < 4; ++im) sMax[half][wm + im * 16 + r] = am[im];
  }
  __syncthreads();

  // ---- quantize + pack + store h8; write scales ----
#pragma unroll
  for (int im = 0; im < 4; ++im) {
    const int lr = wm + im * 16 + r;
    const int gm = bm + lr;
    const float amv = fmaxf(fmaxf(sMax[0][lr], sMax[1][lr]), 1e-20f);
    if (half == 0 && q == 0)
      scales4[(size_t)gm * 4 + head] = amv * (1.f / 127.f);
    const float qs = 127.f / amv;
    unsigned char* hrow = h8 + (size_t)gm * 512 + bn + wn;
#pragma unroll
    for (int in = 0; in < 4; ++in) {
      int q0 = (int)rintf(acc[im][in][0] * qs);
      int q1 = (int)rintf(acc[im][in][1] * qs);
      int q2 = (int)rintf(acc[im][in][2] * qs);
      int q3 = (int)rintf(acc[im][in][3] * qs);
      unsigned int pk = (q0 & 255) | ((q1 & 255) << 8) |
                        ((q2 & 255) << 16) | ((q3 & 255) << 24);
      *(unsigned int*)(hrow + in * 16 + q * 4) = pk;
    }
  }

  // ---- attention partial dots -> atomics ----
  float4 av[4], dv[4];
#pragma unroll
  for (int in = 0; in < 4; ++in) {
    const int nb = bn + wn + in * 16 + q * 4;
    av[in] = *(const float4*)(a_src + nb);
    dv[in] = *(const float4*)(a_dst + nb);
  }
#pragma unroll
  for (int im = 0; im < 4; ++im) {
    float s = 0.f, d = 0.f;
#pragma unroll
    for (int in = 0; in < 4; ++in) {
      s += acc[im][in][0] * av[in].x + acc[im][in][1] * av[in].y
         + acc[im][in][2] * av[in].z + acc[im][in][3] * av[in].w;
      d += acc[im][in][0] * dv[in].x + acc[im][in][1] * dv[in].y
         + acc[im][in][2] * dv[in].z + acc[im][in][3] * dv[in].w;
    }
    s += __shfl_xor(s, 16); s += __shfl_xor(s, 32);
    d += __shfl_xor(d, 16); d += __shfl_xor(d, 32);
    if (q == 0) {
      const int gm = bm + wm + im * 16 + r;
      if (gm < N_NODES) {
        atomicAdd(s_src + (size_t)gm * 4 + head, s);
        atomicAdd(s_dst + (size_t)gm * 4 + head, d);
      }
    }
  }
}

// ---------------------------------------------------------------------------
// Classifier GEMM with fused relu(z)@Wc2 epilogue (round-8 proven) + swizzle
// ---------------------------------------------------------------------------
__global__ __launch_bounds__(256)
void gemm_cls(const unsigned short* __restrict__ A,
              const unsigned short* __restrict__ Bt,
              const float* __restrict__ bc1,
              const float* __restrict__ Wc2,
              float* __restrict__ out,
              int lda)
{
  __shared__ unsigned short As[128 * 32];
  __shared__ unsigned short Bs[128 * 32];
  int bm, bn;
  if (!band_decode(bm, bn)) return;
  const int t    = threadIdx.x;
  const int w    = t >> 6;
  const int lane = t & 63;
  const int r    = lane & 15;
  const int q    = lane >> 4;
  const int wm   = (w >> 1) * 64;
  const int wn   = (w & 1) * 64;

  const int ch0 = (w * 2 + 0) * 64 + lane;
  const int ch1 = (w * 2 + 1) * 64 + lane;
  const unsigned short* gA0 = A + (size_t)(bm + (ch0 >> 2)) * lda + (ch0 & 3) * 8;
  const unsigned short* gA1 = A + (size_t)(bm + (ch1 >> 2)) * lda + (ch1 & 3) * 8;
  const unsigned short* gB0 = Bt + (size_t)(bn + (ch0 >> 2)) * lda + (ch0 & 3) * 8;
  const unsigned short* gB1 = Bt + (size_t)(bn + (ch1 >> 2)) * lda + (ch1 & 3) * 8;
  unsigned short* lA0 = As + (w * 2 + 0) * 512;
  unsigned short* lA1 = As + (w * 2 + 1) * 512;
  unsigned short* lB0 = Bs + (w * 2 + 0) * 512;
  unsigned short* lB1 = Bs + (w * 2 + 1) * 512;

  floatx4 acc[4][4] = {};

  for (int k0 = 0; k0 < lda; k0 += 32) {
    gll16(gA0 + k0, lA0);
    gll16(gA1 + k0, lA1);
    gll16(gB0 + k0, lB0);
    gll16(gB1 + k0, lB1);
    __syncthreads();

    short8 af[4], bfr[4];
#pragma unroll
    for (int im = 0; im < 4; ++im)
      af[im] = *(const short8*)(As + (wm + im * 16 + r) * 32 + q * 8);
#pragma unroll
    for (int in = 0; in < 4; ++in)
      bfr[in] = *(const short8*)(Bs + (wn + in * 16 + r) * 32 + q * 8);
#pragma unroll
    for (int im = 0; im < 4; ++im)
#pragma unroll
      for (int in = 0; in < 4; ++in)
        acc[im][in] = __builtin_amdgcn_mfma_f32_16x16x32_bf16(
            af[im], bfr[in], acc[im][in], 0, 0, 0);
    __syncthreads();
  }

  float p0[16], p1[16];   // [im*4+rr] -> row bm+wm+im*16+q*4+rr
#pragma unroll
  for (int k = 0; k < 16; ++k) { p0[k] = 0.f; p1[k] = 0.f; }

#pragma unroll
  for (int in = 0; in < 4; ++in) {
    const int col = bn + wn + in * 16 + r;
    const float bv = bc1[col];
    const float w0 = Wc2[col * 2 + 0];
    const float w1 = Wc2[col * 2 + 1];
#pragma unroll
    for (int im = 0; im < 4; ++im)
#pragma unroll
      for (int rr = 0; rr < 4; ++rr) {
        float z = fmaxf(acc[im][in][rr] + bv, 0.f);
        p0[im * 4 + rr] += z * w0;
        p1[im * 4 + rr] += z * w1;
      }
  }
#pragma unroll
  for (int o2 = 1; o2 < 16; o2 <<= 1) {
#pragma unroll
    for (int k = 0; k < 16; ++k) {
      p0[k] += __shfl_xor(p0[k], o2);
      p1[k] += __shfl_xor(p1[k], o2);
    }
  }
  if (r == 0) {
#pragma unroll
    for (int im = 0; im < 4; ++im)
#pragma unroll
      for (int rr = 0; rr < 4; ++rr) {
        int row = bm + wm + im * 16 + q * 4 + rr;
        if (row < N_NODES) {
          atomicAdd(out + (size_t)row * 2,     p0[im * 4 + rr]);
          atomicAdd(out + (size_t)row * 2 + 1, p1[im * 4 + rr]);
        }
      }
  }
}

// ---------------------------------------------------------------------------
// Fused segment-softmax + aggregation + bias + LayerNorm + ELU, single pass.
// int8 gather (8B/lane rows); per-(row,head) scale folded into p.
// ---------------------------------------------------------------------------
__global__ __launch_bounds__(256) void k_aggregate(const unsigned char* __restrict__ h8,
                                                   const float* __restrict__ scales4,
                                                   const int* __restrict__ csr_src,
                                                   const int* __restrict__ off,
                                                   const int* __restrict__ deg,
                                                   const float* __restrict__ s_src,
                                                   const float* __restrict__ s_dst,
                                                   const float* __restrict__ bvec,
                                                   const float* __restrict__ gvec,
                                                   const float* __restrict__ bevec,
                                                   unsigned short* __restrict__ out) {
  int node = blockIdx.x * 4 + (threadIdx.x >> 6);
  int lane = threadIdx.x & 63;
  if (node >= N_NODES) return;
  const int o   = __builtin_amdgcn_readfirstlane(off[node]);
  const int cnt = __builtin_amdgcn_readfirstlane(deg[node]);
  const int head = lane >> 4;
  const float sdH = s_dst[(size_t)node * 4 + head];

  float acc[8] = {0.f,0.f,0.f,0.f,0.f,0.f,0.f,0.f};
  float sum = 0.f;

  int s_cur = __builtin_amdgcn_readfirstlane(csr_src[o]);
  uint2 w_cur = ((const uint2*)(h8 + (size_t)s_cur * 512))[lane];
  float f_cur = s_src[(size_t)s_cur * 4 + head];
  float sc_cur = scales4[(size_t)s_cur * 4 + head];

  for (int j = 0; j < cnt; ++j) {
    int jn = (j + 1 < cnt) ? (j + 1) : j;
    int s_nxt = __builtin_amdgcn_readfirstlane(csr_src[o + jn]);
    uint2 w_nxt = ((const uint2*)(h8 + (size_t)s_nxt * 512))[lane];
    float f_nxt = s_src[(size_t)s_nxt * 4 + head];
    float sc_nxt = scales4[(size_t)s_nxt * 4 + head];

    float e = f_cur + sdH;
    e = (e > 0.f) ? e : NEG_SLOPE * e;
    float p = __expf(e);
    sum += p;
    float ps = p * sc_cur;
    int wx = (int)w_cur.x, wy = (int)w_cur.y;
    acc[0] += ps * (float)((wx << 24) >> 24);
    acc[1] += ps * (float)((wx << 16) >> 24);
    acc[2] += ps * (float)((wx <<  8) >> 24);
    acc[3] += ps * (float)( wx        >> 24);
    acc[4] += ps * (float)((wy << 24) >> 24);
    acc[5] += ps * (float)((wy << 16) >> 24);
    acc[6] += ps * (float)((wy <<  8) >> 24);
    acc[7] += ps * (float)( wy        >> 24);

    s_cur = s_nxt; w_cur = w_nxt; f_cur = f_nxt; sc_cur = sc_nxt;
  }

  const float inv = 1.f / sum;
  const float4* bb = (const float4*)bvec;
  float4 b0 = bb[lane*2], b1 = bb[lane*2+1];
  float bl[8] = {b0.x,b0.y,b0.z,b0.w,b1.x,b1.y,b1.z,b1.w};
#pragma unroll
  for (int k = 0; k < 8; ++k) acc[k] = acc[k] * inv + bl[k];

  float ps2 = 0.f, pq = 0.f;
#pragma unroll
  for (int k = 0; k < 8; ++k) { ps2 += acc[k]; pq += acc[k]*acc[k]; }
#pragma unroll
  for (int o2 = 1; o2 < 64; o2 <<= 1) {
    ps2 += __shfl_xor(ps2, o2);
    pq  += __shfl_xor(pq, o2);
  }
  float mu  = ps2 * (1.f/512.f);
  float var = pq * (1.f/512.f) - mu*mu;
  float rstd = rsqrtf(var + LN_EPS);

  const float4* gg = (const float4*)gvec;
  const float4* ee = (const float4*)bevec;
  float4 g0 = gg[lane*2], g1 = gg[lane*2+1];
  float4 e0 = ee[lane*2], e1 = ee[lane*2+1];
  float gs[8] = {g0.x,g0.y,g0.z,g0.w,g1.x,g1.y,g1.z,g1.w};
  float es[8] = {e0.x,e0.y,e0.z,e0.w,e1.x,e1.y,e1.z,e1.w};

  unsigned short us[8];
#pragma unroll
  for (int k = 0; k < 8; ++k) {
    float y = (acc[k] - mu) * rstd * gs[k] + es[k];
    y = (y > 0.f) ? y : expm1f(y);
    us[k] = f2bf(y);
  }
  uint4 w;
  w.x = (unsigned int)us[0] | ((unsigned int)us[1] << 16);
  w.y = (unsigned int)us[2] | ((unsigned int)us[3] << 16);
  w.z = (unsigned int)us[4] | ((unsigned int)us[5] << 16);
  w.w = (unsigned int)us[6] | ((unsigned int)us[7] << 16);
  ((uint4*)(out + (size_t)node * D))[lane] = w;
}

// ---------------------------------------------------------------------------
extern "C" void kernel_launch(void* const* d_in, const int* in_sizes, int n_in,
                              void* d_out, int out_size, void* d_ws, size_t ws_size,
                              hipStream_t stream) {
  const float* x      = (const float*)d_in[0];
  const int*   ei     = (const int*)  d_in[1];
  const float* W1     = (const float*)d_in[2];
  const float* a_src1 = (const float*)d_in[3];
  const float* a_dst1 = (const float*)d_in[4];
  const float* b1     = (const float*)d_in[5];
  const float* g1     = (const float*)d_in[6];
  const float* be1    = (const float*)d_in[7];
  const float* W2     = (const float*)d_in[8];
  const float* a_src2 = (const float*)d_in[9];
  const float* a_dst2 = (const float*)d_in[10];
  const float* b2     = (const float*)d_in[11];
  const float* g2     = (const float*)d_in[12];
  const float* be2    = (const float*)d_in[13];
  const float* Wc1    = (const float*)d_in[14];
  const float* bc1    = (const float*)d_in[15];
  const float* Wc2    = (const float*)d_in[16];
  const float* bc2    = (const float*)d_in[17];
  float* outp = (float*)d_out;

  char* p = (char*)d_ws;
  auto alloc = [&](size_t bytes) {
    char* r = p;
    p += (bytes + 255) & ~(size_t)255;
    return r;
  };
  unsigned short* obuf = (unsigned short*)alloc((size_t)M_PAD * D * 2); // 102.5 MB
  unsigned char*  h8   = (unsigned char*)alloc((size_t)M_PAD * 512);    // 51.2 MB
  unsigned short* w1t  = (unsigned short*)alloc((size_t)512 * K1P * 2);
  unsigned short* w2t  = (unsigned short*)alloc((size_t)512 * 512 * 2);
  unsigned short* wc1t = (unsigned short*)alloc((size_t)512 * 512 * 2);
  int*   csr_src = (int*)  alloc((size_t)E_TOT * 4);                    // 6.8 MB
  int*   deg     = (int*)  alloc((size_t)N_NODES * 4);
  int*   off     = (int*)  alloc((size_t)N_NODES * 4);
  int*   pos     = (int*)  alloc((size_t)N_NODES * 4);
  int*   counter = (int*)  alloc(256);
  int*   flag    = (int*)  alloc(256);
  float* s_src   = (float*)alloc((size_t)N_NODES * 4 * 4);
  float* s_dst   = (float*)alloc((size_t)N_NODES * 4 * 4);
  float* scales4 = (float*)alloc((size_t)M_PAD * 4 * 4);                // 1.6 MB
  // total ~= 168 MB (within the 270 MB proven in round 8)
  // xb aliases obuf's first 38.4 MB (dead after GEMM-1, then overwritten)
  unsigned short* xb = obuf;

  const int EB = (E_TOT + 255) / 256;
  const int NB = (N_NODES + 255) / 256;
  const int ZB = (N_NODES * 4 + 255) / 256;
  const int NW = (N_NODES + 3) / 4;
  const int GB = 8 * ((N_BANDS + 7) / 8) * 4;   // 3136 swizzled blocks

  // init + dtype probe + CSR build + weight conversion
  k_init  <<<NB, 256, 0, stream>>>(deg, counter, flag);
  k_detect<<<1, 256, 0, stream>>>(ei, flag);
  k_count <<<EB, 256, 0, stream>>>(ei, flag, deg);
  k_alloc <<<NB, 256, 0, stream>>>(deg, off, pos, counter);
  k_fill  <<<EB, 256, 0, stream>>>(ei, flag, pos, csr_src);

  k_cvt_x <<<(N_NODES * K1P + 255) / 256, 256, 0, stream>>>(x, xb);
  k_cvt_wt<<<(512 * K1P + 255) / 256, 256, 0, stream>>>(W1, w1t, FIN, K1P);
  k_cvt_wt<<<(512 * 512 + 255) / 256, 256, 0, stream>>>(W2, w2t, 512, 512);
  k_cvt_wt<<<(512 * 512 + 255) / 256, 256, 0, stream>>>(Wc1, wc1t, 512, 512);
  k_out_init<<<NB, 256, 0, stream>>>(bc2, outp);

  // Layer 1
  k_zero     <<<ZB, 256, 0, stream>>>(s_src, s_dst);
  gemm_fused <<<GB, 256, 0, stream>>>(xb, w1t, a_src1, a_dst1, h8, scales4,
                                      s_src, s_dst, K1P);
  k_aggregate<<<NW, 256, 0, stream>>>(h8, scales4, csr_src, off, deg,
                                      s_src, s_dst, b1, g1, be1, obuf);

  // Layer 2
  k_zero     <<<ZB, 256, 0, stream>>>(s_src, s_dst);
  gemm_fused <<<GB, 256, 0, stream>>>(obuf, w2t, a_src2, a_dst2, h8, scales4,
                                      s_src, s_dst, 512);
  k_aggregate<<<NW, 256, 0, stream>>>(h8, scales4, csr_src, off, deg,
                                      s_src, s_dst, b2, g2, be2, obuf);

  // Classifier (fused relu + @Wc2 + bc2 via atomics)
  gemm_cls   <<<GB, 256, 0, stream>>>(obuf, wc1t, bc1, Wc2, outp, 512);
}

// Round 11
// 1010.734 us; speedup vs baseline: 1.0258x; 1.0258x over previous
//
#include <hip/hip_runtime.h>
#include <math.h>

static constexpr int N_NODES = 100000;
static constexpr int N_EDGES = 1600000;
static constexpr int E_TOT   = N_NODES + N_EDGES;   // edges + self-loops
static constexpr int D   = 512;
static constexpr int FIN = 182;
static constexpr int K1P = 192;                     // FIN padded to mult of 32
static constexpr int M_PAD = 100096;                // 782 * 128
static constexpr float NEG_SLOPE = 0.2f;
static constexpr float LN_EPS = 1e-5f;

typedef __attribute__((ext_vector_type(8))) short short8;
typedef __attribute__((ext_vector_type(4))) float floatx4;

// ---------------- bf16 helpers (storage type: unsigned short) ----------------
__device__ __forceinline__ unsigned short f2bf(float f) {
  unsigned int x = __builtin_bit_cast(unsigned int, f);
  x += 0x7fffu + ((x >> 16) & 1u);   // round-to-nearest-even
  return (unsigned short)(x >> 16);
}
__device__ __forceinline__ void unpack2(unsigned int w, float& lo, float& hi) {
  lo = __builtin_bit_cast(float, w << 16);
  hi = __builtin_bit_cast(float, w & 0xffff0000u);
}

// async global->LDS, 16B per lane; LDS dest = wave-uniform base + lane*16
typedef __attribute__((address_space(1))) const void gv_t;
typedef __attribute__((address_space(3))) void lv_t;
__device__ __forceinline__ void gll16(const void* g, void* l) {
  __builtin_amdgcn_global_load_lds((gv_t*)g, (lv_t*)l, 16, 0, 0);
}

// ---------------------------------------------------------------------------
// init + edge-index dtype probe (single block, sampled, no atomic storm)
// ---------------------------------------------------------------------------
__global__ __launch_bounds__(256) void k_init(int* __restrict__ deg,
                                              int* __restrict__ counter,
                                              int* __restrict__ flag) {
  int i = blockIdx.x * 256 + threadIdx.x;
  if (i < N_NODES) deg[i] = 0;
  if (i == 0) { *counter = 0; *flag = 0; }
}

__global__ __launch_bounds__(256) void k_detect(const int* __restrict__ ei,
                                                int* __restrict__ flag) {
  bool nz = false;
#pragma unroll
  for (int r = 0; r < 8; ++r) {
    int i = threadIdx.x + r * 256;          // sample edges 0..2047
    nz |= (ei[2 * i + 1] != 0);
  }
  __shared__ int sh[4];
  int wv = threadIdx.x >> 6;
  if ((threadIdx.x & 63) == 0) sh[wv] = 0;
  __syncthreads();
  if (__any(nz) && (threadIdx.x & 63) == 0) sh[wv] = 1;
  __syncthreads();
  if (threadIdx.x == 0) *flag = sh[0] | sh[1] | sh[2] | sh[3];
}

__device__ __forceinline__ int edge_src(const int* ei, int f, int i) {
  return f ? ei[i] : ei[2 * i];
}
__device__ __forceinline__ int edge_dst(const int* ei, int f, int i) {
  return f ? ei[N_EDGES + i] : ei[2 * (N_EDGES + i)];
}

// ---------------------------------------------------------------------------
// CSR build grouped by dst (range order irrelevant -> atomic range alloc)
// ---------------------------------------------------------------------------
__global__ __launch_bounds__(256) void k_count(const int* __restrict__ ei,
                                               const int* __restrict__ flag,
                                               int* __restrict__ deg) {
  int i = blockIdx.x * 256 + threadIdx.x;
  if (i >= E_TOT) return;
  int f = *flag;
  int d = (i < N_EDGES) ? edge_dst(ei, f, i) : (i - N_EDGES);
  atomicAdd(deg + d, 1);
}

__global__ __launch_bounds__(256) void k_alloc(const int* __restrict__ deg,
                                               int* __restrict__ off,
                                               int* __restrict__ pos,
                                               int* __restrict__ counter) {
  int i = blockIdx.x * 256 + threadIdx.x;
  if (i >= N_NODES) return;
  int r = atomicAdd(counter, deg[i]);
  off[i] = r;
  pos[i] = r;
}

__global__ __launch_bounds__(256) void k_fill(const int* __restrict__ ei,
                                              const int* __restrict__ flag,
                                              int* __restrict__ pos,
                                              int* __restrict__ csr_src) {
  int i = blockIdx.x * 256 + threadIdx.x;
  if (i >= E_TOT) return;
  int f = *flag;
  int s, d;
  if (i < N_EDGES) { s = edge_src(ei, f, i); d = edge_dst(ei, f, i); }
  else             { s = d = i - N_EDGES; }
  int slot = atomicAdd(pos + d, 1);
  csr_src[slot] = s;
}

// ---------------------------------------------------------------------------
// conversion kernels (one-shot, tiny)
// ---------------------------------------------------------------------------
__global__ __launch_bounds__(256) void k_cvt_x(const float* __restrict__ x,
                                               unsigned short* __restrict__ xb) {
  int i = blockIdx.x * 256 + threadIdx.x;
  if (i >= N_NODES * K1P) return;
  int row = i / K1P, col = i - row * K1P;
  float v = (col < FIN) ? x[(size_t)row * FIN + col] : 0.f;
  xb[i] = f2bf(v);
}

__global__ __launch_bounds__(256) void k_cvt_wt(const float* __restrict__ W,
                                                unsigned short* __restrict__ Wt,
                                                int K, int Kpad) {
  int i = blockIdx.x * 256 + threadIdx.x;
  if (i >= 512 * Kpad) return;
  int n = i / Kpad, k = i - n * Kpad;
  Wt[i] = f2bf(k < K ? W[(size_t)k * 512 + n] : 0.f);
}

// out[n,0:2] initialized to bc2 (atomic accumulation target for gemm_cls)
__global__ __launch_bounds__(256) void k_out_init(const float* __restrict__ bc2,
                                                  float* __restrict__ out) {
  int i = blockIdx.x * 256 + threadIdx.x;
  if (i < N_NODES) {
    float2 v; v.x = bc2[0]; v.y = bc2[1];
    ((float2*)out)[i] = v;
  }
}

// ---------------------------------------------------------------------------
// bf16 MFMA GEMM (round-8 proven): C[M_PAD,512] = A[M_PAD,lda] @ Bt[512,lda]^T
// ---------------------------------------------------------------------------
__global__ __launch_bounds__(256)
void gemm_mfma(const unsigned short* __restrict__ A,
               const unsigned short* __restrict__ Bt,
               unsigned short* __restrict__ C,
               int lda)
{
  __shared__ unsigned short As[128 * 32];   // [m][k] 8 KB
  __shared__ unsigned short Bs[128 * 32];   // [n][k] 8 KB
  const int t    = threadIdx.x;
  const int w    = t >> 6;
  const int lane = t & 63;
  const int r    = lane & 15;
  const int q    = lane >> 4;
  const int bm   = blockIdx.y * 128;
  const int bn   = blockIdx.x * 128;
  const int wm   = (w >> 1) * 64;
  const int wn   = (w & 1) * 64;

  const int ch0 = (w * 2 + 0) * 64 + lane;
  const int ch1 = (w * 2 + 1) * 64 + lane;
  const unsigned short* gA0 = A + (size_t)(bm + (ch0 >> 2)) * lda + (ch0 & 3) * 8;
  const unsigned short* gA1 = A + (size_t)(bm + (ch1 >> 2)) * lda + (ch1 & 3) * 8;
  const unsigned short* gB0 = Bt + (size_t)(bn + (ch0 >> 2)) * lda + (ch0 & 3) * 8;
  const unsigned short* gB1 = Bt + (size_t)(bn + (ch1 >> 2)) * lda + (ch1 & 3) * 8;
  unsigned short* lA0 = As + (w * 2 + 0) * 512;
  unsigned short* lA1 = As + (w * 2 + 1) * 512;
  unsigned short* lB0 = Bs + (w * 2 + 0) * 512;
  unsigned short* lB1 = Bs + (w * 2 + 1) * 512;

  floatx4 acc[4][4] = {};

  for (int k0 = 0; k0 < lda; k0 += 32) {
    gll16(gA0 + k0, lA0);
    gll16(gA1 + k0, lA1);
    gll16(gB0 + k0, lB0);
    gll16(gB1 + k0, lB1);
    __syncthreads();

    short8 af[4], bfr[4];
#pragma unroll
    for (int im = 0; im < 4; ++im)
      af[im] = *(const short8*)(As + (wm + im * 16 + r) * 32 + q * 8);
#pragma unroll
    for (int in = 0; in < 4; ++in)
      bfr[in] = *(const short8*)(Bs + (wn + in * 16 + r) * 32 + q * 8);
#pragma unroll
    for (int im = 0; im < 4; ++im)
#pragma unroll
      for (int in = 0; in < 4; ++in)
        acc[im][in] = __builtin_amdgcn_mfma_f32_16x16x32_bf16(
            af[im], bfr[in], acc[im][in], 0, 0, 0);
    __syncthreads();
  }

  // epilogue: C/D layout col=lane&15, row=q*4+reg
#pragma unroll
  for (int in = 0; in < 4; ++in) {
    const int col = bn + wn + in * 16 + r;
#pragma unroll
    for (int im = 0; im < 4; ++im) {
      const size_t rowbase = (size_t)(bm + wm + im * 16 + q * 4) * 512 + col;
#pragma unroll
      for (int rr = 0; rr < 4; ++rr)
        C[rowbase + (size_t)rr * 512] = f2bf(acc[im][in][rr]);
    }
  }
}

// ---------------------------------------------------------------------------
// Classifier GEMM with fused relu(z)@Wc2 epilogue (round-8 proven)
// ---------------------------------------------------------------------------
__global__ __launch_bounds__(256)
void gemm_cls(const unsigned short* __restrict__ A,
              const unsigned short* __restrict__ Bt,
              const float* __restrict__ bc1,
              const float* __restrict__ Wc2,
              float* __restrict__ out,
              int lda)
{
  __shared__ unsigned short As[128 * 32];
  __shared__ unsigned short Bs[128 * 32];
  const int t    = threadIdx.x;
  const int w    = t >> 6;
  const int lane = t & 63;
  const int r    = lane & 15;
  const int q    = lane >> 4;
  const int bm   = blockIdx.y * 128;
  const int bn   = blockIdx.x * 128;
  const int wm   = (w >> 1) * 64;
  const int wn   = (w & 1) * 64;

  const int ch0 = (w * 2 + 0) * 64 + lane;
  const int ch1 = (w * 2 + 1) * 64 + lane;
  const unsigned short* gA0 = A + (size_t)(bm + (ch0 >> 2)) * lda + (ch0 & 3) * 8;
  const unsigned short* gA1 = A + (size_t)(bm + (ch1 >> 2)) * lda + (ch1 & 3) * 8;
  const unsigned short* gB0 = Bt + (size_t)(bn + (ch0 >> 2)) * lda + (ch0 & 3) * 8;
  const unsigned short* gB1 = Bt + (size_t)(bn + (ch1 >> 2)) * lda + (ch1 & 3) * 8;
  unsigned short* lA0 = As + (w * 2 + 0) * 512;
  unsigned short* lA1 = As + (w * 2 + 1) * 512;
  unsigned short* lB0 = Bs + (w * 2 + 0) * 512;
  unsigned short* lB1 = Bs + (w * 2 + 1) * 512;

  floatx4 acc[4][4] = {};

  for (int k0 = 0; k0 < lda; k0 += 32) {
    gll16(gA0 + k0, lA0);
    gll16(gA1 + k0, lA1);
    gll16(gB0 + k0, lB0);
    gll16(gB1 + k0, lB1);
    __syncthreads();

    short8 af[4], bfr[4];
#pragma unroll
    for (int im = 0; im < 4; ++im)
      af[im] = *(const short8*)(As + (wm + im * 16 + r) * 32 + q * 8);
#pragma unroll
    for (int in = 0; in < 4; ++in)
      bfr[in] = *(const short8*)(Bs + (wn + in * 16 + r) * 32 + q * 8);
#pragma unroll
    for (int im = 0; im < 4; ++im)
#pragma unroll
      for (int in = 0; in < 4; ++in)
        acc[im][in] = __builtin_amdgcn_mfma_f32_16x16x32_bf16(
            af[im], bfr[in], acc[im][in], 0, 0, 0);
    __syncthreads();
  }

  float p0[16], p1[16];   // [im*4+rr] -> row bm+wm+im*16+q*4+rr
#pragma unroll
  for (int k = 0; k < 16; ++k) { p0[k] = 0.f; p1[k] = 0.f; }

#pragma unroll
  for (int in = 0; in < 4; ++in) {
    const int col = bn + wn + in * 16 + r;
    const float bv = bc1[col];
    const float w0 = Wc2[col * 2 + 0];
    const float w1 = Wc2[col * 2 + 1];
#pragma unroll
    for (int im = 0; im < 4; ++im)
#pragma unroll
      for (int rr = 0; rr < 4; ++rr) {
        float z = fmaxf(acc[im][in][rr] + bv, 0.f);
        p0[im * 4 + rr] += z * w0;
        p1[im * 4 + rr] += z * w1;
      }
  }
#pragma unroll
  for (int o2 = 1; o2 < 16; o2 <<= 1) {
#pragma unroll
    for (int k = 0; k < 16; ++k) {
      p0[k] += __shfl_xor(p0[k], o2);
      p1[k] += __shfl_xor(p1[k], o2);
    }
  }
  if (r == 0) {
#pragma unroll
    for (int im = 0; im < 4; ++im)
#pragma unroll
      for (int rr = 0; rr < 4; ++rr) {
        int row = bm + wm + im * 16 + q * 4 + rr;
        if (row < N_NODES) {
          atomicAdd(out + (size_t)row * 2,     p0[im * 4 + rr]);
          atomicAdd(out + (size_t)row * 2 + 1, p1[im * 4 + rr]);
        }
      }
  }
}

// ---------------------------------------------------------------------------
// Per-node attention dots + int8 quantization of h (excess-128, per-HEAD
// absmax scale) + fused (s_src, scale) float2 emit.
// ---------------------------------------------------------------------------
__global__ __launch_bounds__(256) void k_sdots(const unsigned short* __restrict__ h,
                                               const float* __restrict__ a_src,
                                               const float* __restrict__ a_dst,
                                               float2* __restrict__ ssc,
                                               float* __restrict__ s_dst,
                                               unsigned char* __restrict__ h8) {
  int node = blockIdx.x * 4 + (threadIdx.x >> 6);
  int lane = threadIdx.x & 63;
  if (node >= N_NODES) return;
  uint4 w = ((const uint4*)(h + (size_t)node * D))[lane];
  float v[8];
  unpack2(w.x, v[0], v[1]); unpack2(w.y, v[2], v[3]);
  unpack2(w.z, v[4], v[5]); unpack2(w.w, v[6], v[7]);

  // per-head absmax (16 lanes per head)
  float am = 0.f;
#pragma unroll
  for (int k = 0; k < 8; ++k) am = fmaxf(am, fabsf(v[k]));
#pragma unroll
  for (int o = 1; o < 16; o <<= 1) am = fmaxf(am, __shfl_xor(am, o));
  am = fmaxf(am, 1e-20f);
  const float qsc = 127.f / am;
  int qv[8];
#pragma unroll
  for (int k = 0; k < 8; ++k) qv[k] = (int)rintf(v[k] * qsc) + 128;
  uint2 pk;
  pk.x = (qv[0] & 255) | ((qv[1] & 255) << 8) | ((qv[2] & 255) << 16) | ((qv[3] & 255) << 24);
  pk.y = (qv[4] & 255) | ((qv[5] & 255) << 8) | ((qv[6] & 255) << 16) | ((qv[7] & 255) << 24);
  ((uint2*)(h8 + (size_t)node * 512))[lane] = pk;

  const float4* as = (const float4*)a_src;
  const float4* ad = (const float4*)a_dst;
  float4 s0 = as[lane*2], s1 = as[lane*2+1];
  float4 d0 = ad[lane*2], d1 = ad[lane*2+1];
  float ps = v[0]*s0.x + v[1]*s0.y + v[2]*s0.z + v[3]*s0.w
           + v[4]*s1.x + v[5]*s1.y + v[6]*s1.z + v[7]*s1.w;
  float pd = v[0]*d0.x + v[1]*d0.y + v[2]*d0.z + v[3]*d0.w
           + v[4]*d1.x + v[5]*d1.y + v[6]*d1.z + v[7]*d1.w;
#pragma unroll
  for (int o = 1; o < 16; o <<= 1) {
    ps += __shfl_xor(ps, o);
    pd += __shfl_xor(pd, o);
  }
  if ((lane & 15) == 0) {
    int hh = lane >> 4;
    float2 sc; sc.x = ps; sc.y = am * (1.f / 127.f);
    ssc[node*4 + hh] = sc;
    s_dst[node*4 + hh] = pd;
  }
}

// ---------------------------------------------------------------------------
// Fused segment-softmax + aggregation + bias + LayerNorm + ELU, single pass.
// h8 is excess-128 ubyte: decode via (w&255)-style patterns -> the compiler's
// v_cvt_f32_ubyte0..3 idiom (1 op/channel); exact -128*sum_ps correction
// after the loop. (score,scale) fused in one 8B ssc load per edge.
// ---------------------------------------------------------------------------
__global__ __launch_bounds__(256) void k_aggregate(const unsigned char* __restrict__ h8,
                                                   const float2* __restrict__ ssc,
                                                   const int* __restrict__ csr_src,
                                                   const int* __restrict__ off,
                                                   const int* __restrict__ deg,
                                                   const float* __restrict__ s_dst,
                                                   const float* __restrict__ bvec,
                                                   const float* __restrict__ gvec,
                                                   const float* __restrict__ bevec,
                                                   unsigned short* __restrict__ out) {
  int node = blockIdx.x * 4 + (threadIdx.x >> 6);
  int lane = threadIdx.x & 63;
  if (node >= N_NODES) return;
  const int o   = __builtin_amdgcn_readfirstlane(off[node]);
  const int cnt = __builtin_amdgcn_readfirstlane(deg[node]);
  const int head = lane >> 4;
  const float sdH = s_dst[(size_t)node * 4 + head];

  float acc[8] = {0.f,0.f,0.f,0.f,0.f,0.f,0.f,0.f};
  float sum = 0.f, sum_ps = 0.f;

  int s_cur = __builtin_amdgcn_readfirstlane(csr_src[o]);
  uint2 w_cur = ((const uint2*)(h8 + (size_t)s_cur * 512))[lane];
  float2 fc_cur = ssc[(size_t)s_cur * 4 + head];

  for (int j = 0; j < cnt; ++j) {
    int jn = (j + 1 < cnt) ? (j + 1) : j;
    int s_nxt = __builtin_amdgcn_readfirstlane(csr_src[o + jn]);
    uint2 w_nxt = ((const uint2*)(h8 + (size_t)s_nxt * 512))[lane];
    float2 fc_nxt = ssc[(size_t)s_nxt * 4 + head];

    float e = fc_cur.x + sdH;
    e = (e > 0.f) ? e : NEG_SLOPE * e;
    float p = __expf(e);
    sum += p;
    float ps = p * fc_cur.y;
    sum_ps += ps;
    unsigned int wx = w_cur.x, wy = w_cur.y;
    acc[0] += ps * (float)( wx        & 255u);
    acc[1] += ps * (float)((wx >>  8) & 255u);
    acc[2] += ps * (float)((wx >> 16) & 255u);
    acc[3] += ps * (float)( wx >> 24);
    acc[4] += ps * (float)( wy        & 255u);
    acc[5] += ps * (float)((wy >>  8) & 255u);
    acc[6] += ps * (float)((wy >> 16) & 255u);
    acc[7] += ps * (float)( wy >> 24);

    s_cur = s_nxt; w_cur = w_nxt; fc_cur = fc_nxt;
  }

  const float inv = 1.f / sum;
  const float4* bb = (const float4*)bvec;
  float4 b0 = bb[lane*2], b1 = bb[lane*2+1];
  float bl[8] = {b0.x,b0.y,b0.z,b0.w,b1.x,b1.y,b1.z,b1.w};
#pragma unroll
  for (int k = 0; k < 8; ++k)
    acc[k] = (acc[k] - 128.f * sum_ps) * inv + bl[k];

  float ps2 = 0.f, pq = 0.f;
#pragma unroll
  for (int k = 0; k < 8; ++k) { ps2 += acc[k]; pq += acc[k]*acc[k]; }
#pragma unroll
  for (int o2 = 1; o2 < 64; o2 <<= 1) {
    ps2 += __shfl_xor(ps2, o2);
    pq  += __shfl_xor(pq, o2);
  }
  float mu  = ps2 * (1.f/512.f);
  float var = pq * (1.f/512.f) - mu*mu;
  float rstd = rsqrtf(var + LN_EPS);

  const float4* gg = (const float4*)gvec;
  const float4* ee = (const float4*)bevec;
  float4 g0 = gg[lane*2], g1 = gg[lane*2+1];
  float4 e0 = ee[lane*2], e1 = ee[lane*2+1];
  float gs[8] = {g0.x,g0.y,g0.z,g0.w,g1.x,g1.y,g1.z,g1.w};
  float es[8] = {e0.x,e0.y,e0.z,e0.w,e1.x,e1.y,e1.z,e1.w};

  unsigned short us[8];
#pragma unroll
  for (int k = 0; k < 8; ++k) {
    float y = (acc[k] - mu) * rstd * gs[k] + es[k];
    y = (y > 0.f) ? y : expm1f(y);
    us[k] = f2bf(y);
  }
  uint4 w;
  w.x = (unsigned int)us[0] | ((unsigned int)us[1] << 16);
  w.y = (unsigned int)us[2] | ((unsigned int)us[3] << 16);
  w.z = (unsigned int)us[4] | ((unsigned int)us[5] << 16);
  w.w = (unsigned int)us[6] | ((unsigned int)us[7] << 16);
  ((uint4*)(out + (size_t)node * D))[lane] = w;
}

// ---------------------------------------------------------------------------
extern "C" void kernel_launch(void* const* d_in, const int* in_sizes, int n_in,
                              void* d_out, int out_size, void* d_ws, size_t ws_size,
                              hipStream_t stream) {
  const float* x      = (const float*)d_in[0];
  const int*   ei     = (const int*)  d_in[1];
  const float* W1     = (const float*)d_in[2];
  const float* a_src1 = (const float*)d_in[3];
  const float* a_dst1 = (const float*)d_in[4];
  const float* b1     = (const float*)d_in[5];
  const float* g1     = (const float*)d_in[6];
  const float* be1    = (const float*)d_in[7];
  const float* W2     = (const float*)d_in[8];
  const float* a_src2 = (const float*)d_in[9];
  const float* a_dst2 = (const float*)d_in[10];
  const float* b2     = (const float*)d_in[11];
  const float* g2     = (const float*)d_in[12];
  const float* be2    = (const float*)d_in[13];
  const float* Wc1    = (const float*)d_in[14];
  const float* bc1    = (const float*)d_in[15];
  const float* Wc2    = (const float*)d_in[16];
  const float* bc2    = (const float*)d_in[17];
  float* outp = (float*)d_out;

  char* p = (char*)d_ws;
  auto alloc = [&](size_t bytes) {
    char* r = p;
    p += (bytes + 255) & ~(size_t)255;
    return r;
  };
  unsigned short* hbuf = (unsigned short*)alloc((size_t)M_PAD * D * 2); // 102.5 MB
  unsigned short* obuf = (unsigned short*)alloc((size_t)M_PAD * D * 2); // 102.5 MB
  unsigned short* w1t  = (unsigned short*)alloc((size_t)512 * K1P * 2);
  unsigned short* w2t  = (unsigned short*)alloc((size_t)512 * 512 * 2);
  unsigned short* wc1t = (unsigned short*)alloc((size_t)512 * 512 * 2);
  int*   csr_src = (int*)  alloc((size_t)E_TOT * 4);                    // 6.8 MB
  int*   deg     = (int*)  alloc((size_t)N_NODES * 4);
  int*   off     = (int*)  alloc((size_t)N_NODES * 4);
  int*   pos     = (int*)  alloc((size_t)N_NODES * 4);
  int*   counter = (int*)  alloc(256);
  int*   flag    = (int*)  alloc(256);
  float2* ssc    = (float2*)alloc((size_t)N_NODES * 4 * 8);             // 3.2 MB
  float* s_dst   = (float*)alloc((size_t)N_NODES * 4 * 4);              // 1.6 MB
  unsigned char* h8 = (unsigned char*)alloc((size_t)M_PAD * 512);       // 51.2 MB
  // total ~= 270.5 MB (round 7/8 proved >= ~270 MB available)
  // xb aliases obuf's first 38.4 MB (dead after GEMM-1, then overwritten)
  unsigned short* xb = obuf;

  const int EB = (E_TOT + 255) / 256;
  const int NB = (N_NODES + 255) / 256;
  const int NW = (N_NODES + 3) / 4;
  dim3 gg(4, M_PAD / 128);

  // init + dtype probe + CSR build + weight conversion
  k_init  <<<NB, 256, 0, stream>>>(deg, counter, flag);
  k_detect<<<1, 256, 0, stream>>>(ei, flag);
  k_count <<<EB, 256, 0, stream>>>(ei, flag, deg);
  k_alloc <<<NB, 256, 0, stream>>>(deg, off, pos, counter);
  k_fill  <<<EB, 256, 0, stream>>>(ei, flag, pos, csr_src);

  k_cvt_x <<<(N_NODES * K1P + 255) / 256, 256, 0, stream>>>(x, xb);
  k_cvt_wt<<<(512 * K1P + 255) / 256, 256, 0, stream>>>(W1, w1t, FIN, K1P);
  k_cvt_wt<<<(512 * 512 + 255) / 256, 256, 0, stream>>>(W2, w2t, 512, 512);
  k_cvt_wt<<<(512 * 512 + 255) / 256, 256, 0, stream>>>(Wc1, wc1t, 512, 512);
  k_out_init<<<NB, 256, 0, stream>>>(bc2, outp);

  // Layer 1
  gemm_mfma  <<<gg, 256, 0, stream>>>(xb, w1t, hbuf, K1P);
  k_sdots    <<<NW, 256, 0, stream>>>(hbuf, a_src1, a_dst1, ssc, s_dst, h8);
  k_aggregate<<<NW, 256, 0, stream>>>(h8, ssc, csr_src, off, deg,
                                      s_dst, b1, g1, be1, obuf);

  // Layer 2
  gemm_mfma  <<<gg, 256, 0, stream>>>(obuf, w2t, hbuf, 512);
  k_sdots    <<<NW, 256, 0, stream>>>(hbuf, a_src2, a_dst2, ssc, s_dst, h8);
  k_aggregate<<<NW, 256, 0, stream>>>(h8, ssc, csr_src, off, deg,
                                      s_dst, b2, g2, be2, obuf);

  // Classifier (fused relu + @Wc2 + bc2 via atomics)
  gemm_cls   <<<gg, 256, 0, stream>>>(obuf, wc1t, bc1, Wc2, outp, 512);
}